// Round 8
// baseline (1412.263 us; speedup 1.0000x reference)
//
#include <hip/hip_runtime.h>
#include <cstdint>
#include <cstddef>

// PConv, round 8: INSTRUMENTED DECOMPOSITION.
// Graph: cvt -> A(loads-only x4) -> B(store-only x4) -> D(vec-gather loads x4)
//        -> C(full R7 kernel x3, correct output written last).
// Repeats lift each dispatch above the ~245us fill kernels so all appear in
// rocprof top-5 with their own counters. d_out is correct after C.

namespace {
constexpr int B_   = 2;
constexpr int N_   = 50000;
constexpr int M_   = 50000;
constexpr int KNB  = 16;
constexpr int CIN  = 64;
constexpr int COUT = 67 * 16;      // 1072
constexpr int PAIRS = B_ * M_;     // 100000
constexpr int FELEMS = B_ * N_ * CIN;   // 6,400,000
constexpr size_t TBL_BYTES  = (size_t)FELEMS * 2;        // 12.8 MB
constexpr size_t SINK_OFF_A = 16u  * 1024 * 1024;        // byte offsets in ws
constexpr size_t SINK_OFF_D = 20u  * 1024 * 1024;
}

typedef unsigned int u32;
typedef float  f32x4  __attribute__((ext_vector_type(4)));
typedef short  short8 __attribute__((ext_vector_type(8)));
typedef u32    u32x4  __attribute__((ext_vector_type(4)));
typedef u32    u32x2  __attribute__((ext_vector_type(2)));

struct IdxS   { int v[16]; };
struct StageT { unsigned short bg[4][8]; float ad[8]; float wf[8]; };
struct StageF { float bg[4][8]; float ad[8]; float wf[8]; };

static __device__ __forceinline__ short8 pack_bf8(const float* x) {
  u32x4 w;
  #pragma unroll
  for (int q = 0; q < 4; ++q)
    w[q] = __builtin_amdgcn_perm(__builtin_bit_cast(u32, x[2*q+1]),
                                 __builtin_bit_cast(u32, x[2*q]),
                                 0x07060302u);
  return __builtin_bit_cast(short8, w);
}

static __device__ __forceinline__ u32 bfrne(float x) {
  u32 u = __builtin_bit_cast(u32, x);
  return (u + 0x7FFFu + ((u >> 16) & 1u)) >> 16;
}

// ---------------- pre-pass ----------------
__global__ __launch_bounds__(256)
void cvt_feat_bf16(const float* __restrict__ src, unsigned short* __restrict__ dst) {
  const int n4 = FELEMS / 4;
  int i = blockIdx.x * blockDim.x + threadIdx.x;
  const int stride = gridDim.x * blockDim.x;
  const f32x4* s4 = reinterpret_cast<const f32x4*>(src);
  for (; i < n4; i += stride) {
    f32x4 v = s4[i];
    u32x2 w;
    w[0] = bfrne(v[0]) | (bfrne(v[1]) << 16);
    w[1] = bfrne(v[2]) | (bfrne(v[3]) << 16);
    *reinterpret_cast<u32x2*>(dst + 4 * (size_t)i) = w;
  }
}

// ---------------- helpers (R7-identical) ----------------
static __device__ __forceinline__ void load_idx(const int* __restrict__ idxp, IdxS& r) {
  #pragma unroll
  for (int j = 0; j < 16; ++j)
    r.v[j] = __builtin_amdgcn_readfirstlane(idxp[j]);
}

static __device__ __forceinline__ void load_stage_t(const unsigned short* __restrict__ fb,
                                                    const float* __restrict__ wnp,
                                                    const float* __restrict__ adp,
                                                    const IdxS& I, int lane, StageT& S) {
  const int cc = lane & 15;
  if (lane < 32) {
    const int hi = lane >> 4;
    int rows[8];
    #pragma unroll
    for (int j = 0; j < 8; ++j) rows[j] = hi ? I.v[j + 8] : I.v[j];
    #pragma unroll
    for (int j = 0; j < 8; ++j) {
      const u32 rb = ((u32)rows[j]) << 6;
      #pragma unroll
      for (int t = 0; t < 4; ++t)
        S.bg[t][j] = fb[rb + (u32)(t * 16 + cc)];
    }
    const u32 woff = (hi ? 128u : 0u) + (u32)cc;
    #pragma unroll
    for (int j = 0; j < 8; ++j)
      S.wf[j] = __builtin_nontemporal_load(wnp + woff + j * 16);
    if (cc < 3) {
      const u32 aoff = (hi ? 24u : 0u) + (u32)cc;
      #pragma unroll
      for (int j = 0; j < 8; ++j)
        S.ad[j] = __builtin_nontemporal_load(adp + aoff + j * 3);
    }
  }
}

static __device__ __forceinline__ void compute_store_t(const StageT& S,
                                                       float* __restrict__ op, int lane) {
  const int cc = lane & 15, g = lane >> 4;
  const int soff = cc * 16 + g * 4;
  const short8 a = pack_bf8(S.wf);
  #pragma unroll
  for (int t = 0; t < 4; ++t) {
    short8 b;
    #pragma unroll
    for (int j = 0; j < 8; ++j) b[j] = (short)S.bg[t][j];
    f32x4 acc = {0.f, 0.f, 0.f, 0.f};
    acc = __builtin_amdgcn_mfma_f32_16x16x32_bf16(a, b, acc, 0, 0, 0);
    __builtin_nontemporal_store(acc, reinterpret_cast<f32x4*>(op + soff + t * 256));
  }
  {
    const short8 b = pack_bf8(S.ad);
    f32x4 acc = {0.f, 0.f, 0.f, 0.f};
    acc = __builtin_amdgcn_mfma_f32_16x16x32_bf16(a, b, acc, 0, 0, 0);
    if (cc < 3)
      __builtin_nontemporal_store(acc, reinterpret_cast<f32x4*>(op + soff + 1024));
  }
}

// ---------------- A: load phase only, x4 ----------------
__global__ __launch_bounds__(256, 4)
void abl_loads(const unsigned short* __restrict__ tbl, const int* __restrict__ inds,
               const float* __restrict__ wnet, const float* __restrict__ addf,
               float* __restrict__ sink)
{
  const int lane = threadIdx.x & 63;
  const int gw = __builtin_amdgcn_readfirstlane(
      (int)((blockIdx.x * blockDim.x + threadIdx.x) >> 6));
  const int nw = (int)((gridDim.x * blockDim.x) >> 6);
  if (gw >= PAIRS) return;

  float acc = 0.f;
  #pragma unroll 1
  for (int r = 0; r < 4; ++r) {
    IdxS iCur, iNext;
    load_idx(inds + (size_t)gw * KNB, iCur);
    for (int p = gw; p < PAIRS; p += nw) {
      const int pn = (p + nw < PAIRS) ? (p + nw) : gw;
      load_idx(inds + (size_t)pn * KNB, iNext);
      const int b = p / M_;
      StageT S = {};
      load_stage_t(tbl + (size_t)b * N_ * CIN, wnet + (size_t)p * 256,
                   addf + (size_t)p * 48, iCur, lane, S);
      int ui = 0;
      #pragma unroll
      for (int t = 0; t < 4; ++t)
        #pragma unroll
        for (int j = 0; j < 8; ++j) ui += S.bg[t][j];
      float fa = 0.f;
      #pragma unroll
      for (int j = 0; j < 8; ++j) fa += S.wf[j] + S.ad[j];
      acc += fa + (float)ui;
      #pragma unroll
      for (int j = 0; j < 16; ++j) iCur.v[j] = iNext.v[j];
    }
  }
  if (lane == 0) sink[gw] = acc;
}

// ---------------- B: compute+store phase only, x4 ----------------
__global__ __launch_bounds__(256, 4)
void abl_store(float* __restrict__ out)
{
  const int lane = threadIdx.x & 63;
  const int gw = __builtin_amdgcn_readfirstlane(
      (int)((blockIdx.x * blockDim.x + threadIdx.x) >> 6));
  const int nw = (int)((gridDim.x * blockDim.x) >> 6);
  if (gw >= PAIRS) return;

  StageT S;                      // loop-invariant synthetic fragments
  #pragma unroll
  for (int t = 0; t < 4; ++t)
    #pragma unroll
    for (int j = 0; j < 8; ++j) S.bg[t][j] = (unsigned short)(0x3f80 + lane + t + j);
  #pragma unroll
  for (int j = 0; j < 8; ++j) { S.ad[j] = 0.5f + j; S.wf[j] = 1.0f + lane * 0.01f; }

  #pragma unroll 1
  for (int r = 0; r < 4; ++r)
    for (int p = gw; p < PAIRS; p += nw)
      compute_store_t(S, out + (size_t)p * COUT, lane);
}

// ---------------- D: alternative vectorized gather, x4 ----------------
__global__ __launch_bounds__(256, 4)
void abl_vecgather(const unsigned short* __restrict__ tbl, const int* __restrict__ inds,
                   float* __restrict__ sink)
{
  const int lane = threadIdx.x & 63;
  const int gw = __builtin_amdgcn_readfirstlane(
      (int)((blockIdx.x * blockDim.x + threadIdx.x) >> 6));
  const int nw = (int)((gridDim.x * blockDim.x) >> 6);
  if (gw >= PAIRS) return;

  const int kr  = lane >> 2;     // row 0..15
  const int seg = lane & 3;      // 16B segment; two loads: seg, seg+4
  u32 acc = 0;
  #pragma unroll 1
  for (int r = 0; r < 4; ++r) {
    IdxS iCur, iNext;
    load_idx(inds + (size_t)gw * KNB, iCur);
    for (int p = gw; p < PAIRS; p += nw) {
      const int pn = (p + nw < PAIRS) ? (p + nw) : gw;
      load_idx(inds + (size_t)pn * KNB, iNext);
      const int b = p / M_;
      const unsigned short* fb = tbl + (size_t)b * N_ * CIN;
      const u32 rb = ((u32)iCur.v[kr]) << 6;
      const u32x4 v0 = *reinterpret_cast<const u32x4*>(fb + rb + seg * 8);
      const u32x4 v1 = *reinterpret_cast<const u32x4*>(fb + rb + 32 + seg * 8);
      #pragma unroll
      for (int q = 0; q < 4; ++q) acc += v0[q] + v1[q];
      #pragma unroll
      for (int j = 0; j < 16; ++j) iCur.v[j] = iNext.v[j];
    }
  }
  if (lane == 0) sink[gw] = (float)acc;
}

// ---------------- C: full kernel (R7), x3 idempotent ----------------
__global__ __launch_bounds__(256, 4)
void pconv8_tbl(const unsigned short* __restrict__ tbl, const int* __restrict__ inds,
                const float* __restrict__ wnet, const float* __restrict__ addf,
                float* __restrict__ out)
{
  const int lane = threadIdx.x & 63;
  const int gw = __builtin_amdgcn_readfirstlane(
      (int)((blockIdx.x * blockDim.x + threadIdx.x) >> 6));
  const int nw = (int)((gridDim.x * blockDim.x) >> 6);
  if (gw >= PAIRS) return;

  #pragma unroll 1
  for (int r = 0; r < 3; ++r) {
    IdxS iCur, iNext;
    load_idx(inds + (size_t)gw * KNB, iCur);
    for (int p = gw; p < PAIRS; p += nw) {
      const int pn = (p + nw < PAIRS) ? (p + nw) : gw;
      load_idx(inds + (size_t)pn * KNB, iNext);
      const int b = p / M_;
      StageT S = {};
      load_stage_t(tbl + (size_t)b * N_ * CIN, wnet + (size_t)p * 256,
                   addf + (size_t)p * 48, iCur, lane, S);
      compute_store_t(S, out + (size_t)p * COUT, lane);
      #pragma unroll
      for (int j = 0; j < 16; ++j) iCur.v[j] = iNext.v[j];
    }
  }
}

// ---------------- fallback (ws too small): R7-f32 single pass ----------------
static __device__ __forceinline__ void load_stage_f(const float* __restrict__ fb,
                                                    const float* __restrict__ wnp,
                                                    const float* __restrict__ adp,
                                                    const IdxS& I, int lane, StageF& S) {
  const int cc = lane & 15;
  if (lane < 32) {
    const int hi = lane >> 4;
    int rows[8];
    #pragma unroll
    for (int j = 0; j < 8; ++j) rows[j] = hi ? I.v[j + 8] : I.v[j];
    #pragma unroll
    for (int j = 0; j < 8; ++j) {
      const u32 rb = ((u32)rows[j]) << 6;
      #pragma unroll
      for (int t = 0; t < 4; ++t)
        S.bg[t][j] = fb[rb + (u32)(t * 16 + cc)];
    }
    const u32 woff = (hi ? 128u : 0u) + (u32)cc;
    #pragma unroll
    for (int j = 0; j < 8; ++j)
      S.wf[j] = __builtin_nontemporal_load(wnp + woff + j * 16);
    if (cc < 3) {
      const u32 aoff = (hi ? 24u : 0u) + (u32)cc;
      #pragma unroll
      for (int j = 0; j < 8; ++j)
        S.ad[j] = __builtin_nontemporal_load(adp + aoff + j * 3);
    }
  }
}

__global__ __launch_bounds__(256, 4)
void pconv8_f32(const float* __restrict__ feat, const int* __restrict__ inds,
                const float* __restrict__ wnet, const float* __restrict__ addf,
                float* __restrict__ out)
{
  const int lane = threadIdx.x & 63;
  const int gw = __builtin_amdgcn_readfirstlane(
      (int)((blockIdx.x * blockDim.x + threadIdx.x) >> 6));
  const int nw = (int)((gridDim.x * blockDim.x) >> 6);
  if (gw >= PAIRS) return;

  IdxS iCur, iNext;
  load_idx(inds + (size_t)gw * KNB, iCur);
  for (int p = gw; p < PAIRS; p += nw) {
    const int pn = (p + nw < PAIRS) ? (p + nw) : gw;
    load_idx(inds + (size_t)pn * KNB, iNext);
    const int b = p / M_;
    StageF S = {};
    load_stage_f(feat + (size_t)b * N_ * CIN, wnet + (size_t)p * 256,
                 addf + (size_t)p * 48, iCur, lane, S);
    // pack + mfma + store (same math as compute_store_t, f32 source)
    const int cc = lane & 15, g = lane >> 4;
    const int soff = cc * 16 + g * 4;
    float* op = out + (size_t)p * COUT;
    const short8 a = pack_bf8(S.wf);
    #pragma unroll
    for (int t = 0; t < 4; ++t) {
      const short8 bb = pack_bf8(S.bg[t]);
      f32x4 acc = {0.f, 0.f, 0.f, 0.f};
      acc = __builtin_amdgcn_mfma_f32_16x16x32_bf16(a, bb, acc, 0, 0, 0);
      __builtin_nontemporal_store(acc, reinterpret_cast<f32x4*>(op + soff + t * 256));
    }
    {
      const short8 bb = pack_bf8(S.ad);
      f32x4 acc = {0.f, 0.f, 0.f, 0.f};
      acc = __builtin_amdgcn_mfma_f32_16x16x32_bf16(a, bb, acc, 0, 0, 0);
      if (cc < 3)
        __builtin_nontemporal_store(acc, reinterpret_cast<f32x4*>(op + soff + 1024));
    }
    #pragma unroll
    for (int j = 0; j < 16; ++j) iCur.v[j] = iNext.v[j];
  }
}

extern "C" void kernel_launch(void* const* d_in, const int* in_sizes, int n_in,
                              void* d_out, int out_size, void* d_ws, size_t ws_size,
                              hipStream_t stream) {
  const float* feat = (const float*)d_in[0];
  const int*   inds = (const int*)d_in[1];
  const float* wnet = (const float*)d_in[2];
  const float* addf = (const float*)d_in[3];
  float* outp = (float*)d_out;

  dim3 grid(4096), block(256);
  if (ws_size >= SINK_OFF_D + (size_t)16384 * 4) {
    unsigned short* tbl = (unsigned short*)d_ws;
    float* sinkA = (float*)((char*)d_ws + SINK_OFF_A);
    float* sinkD = (float*)((char*)d_ws + SINK_OFF_D);
    hipLaunchKernelGGL(cvt_feat_bf16, dim3(2048), dim3(256), 0, stream, feat, tbl);
    hipLaunchKernelGGL(abl_loads,     grid, block, 0, stream, tbl, inds, wnet, addf, sinkA);
    hipLaunchKernelGGL(abl_store,     grid, block, 0, stream, outp);
    hipLaunchKernelGGL(abl_vecgather, grid, block, 0, stream, tbl, inds, sinkD);
    hipLaunchKernelGGL(pconv8_tbl,    grid, block, 0, stream, tbl, inds, wnet, addf, outp);
  } else {
    hipLaunchKernelGGL(pconv8_f32, grid, block, 0, stream,
                       feat, inds, wnet, addf, outp);
  }
}